// Round 4
// baseline (714.228 us; speedup 1.0000x reference)
//
#include <hip/hip_runtime.h>

// Problem constants (fixed by reference)
#define NTOK   8192
#define HIDDEN 2048
#define NHEAD  32
#define HDIM   64
#define BLK    256
#define NBLK   32          // NTOK / BLK
#define QKVW   6144        // 3 * HIDDEN

typedef unsigned short ushort_t;
typedef __attribute__((ext_vector_type(8))) short bf16x8;   // 8 bf16 = 4 VGPRs
typedef __attribute__((ext_vector_type(4))) float floatx4;  // MFMA C/D
typedef __attribute__((ext_vector_type(4))) unsigned short ushortx4;

#define MFMA16(a, b, c) __builtin_amdgcn_mfma_f32_16x16x32_bf16(a, b, c, 0, 0, 0)

// slope[h] = 2^(-0.25*(h+1)) * (1 - 0/79 + 1e-5)
__device__ __forceinline__ float head_slope(int h) {
    return exp2f(-0.25f * (float)(h + 1)) * 1.00001f;
}

__device__ __forceinline__ ushort_t f2bf(float x) {
    unsigned int u = __float_as_uint(x);
    unsigned int r = (u + 0x7FFFu + ((u >> 16) & 1u)) >> 16;   // RNE
    return (ushort_t)r;
}
__device__ __forceinline__ float bf2f(ushort_t x) {
    return __uint_as_float(((unsigned int)x) << 16);
}
__device__ __forceinline__ void store1(float* p, float v) { *p = v; }
__device__ __forceinline__ void store1(ushort_t* p, float v) { *p = f2bf(v); }

// async global->LDS, 16B per lane (lds dest = wave-uniform base + lane*16;
// global source is per-lane)
#define GLOAD_LDS16(g, l)                                              \
    __builtin_amdgcn_global_load_lds(                                  \
        (const __attribute__((address_space(1))) void*)(g),            \
        (__attribute__((address_space(3))) void*)(l), 16, 0, 0)

// ---------------------------------------------------------------------------
// fp32 -> bf16 convert, 8 elems/thread.
// ---------------------------------------------------------------------------
__global__ __launch_bounds__(256) void cvt_bf16(
    const float* __restrict__ in, ushort_t* __restrict__ out, int n8) {
    int i = blockIdx.x * 256 + threadIdx.x;
    if (i >= n8) return;
    long base = (long)i * 8;
    float4 a = *(const float4*)(in + base);
    float4 b = *(const float4*)(in + base + 4);
    ushort4 u0 = {f2bf(a.x), f2bf(a.y), f2bf(a.z), f2bf(a.w)};
    ushort4 u1 = {f2bf(b.x), f2bf(b.y), f2bf(b.z), f2bf(b.w)};
    *(ushort4*)(out + base) = u0;
    *(ushort4*)(out + base + 4) = u1;
}

// ---------------------------------------------------------------------------
// 256x256-tile bf16 MFMA GEMM, 8-phase schedule with cross-wave LDS/MFMA
// overlap. C[M,N] = epi(A[M,K] @ B[N,K]^T), fp32 acc. 512 threads = 8 waves
// (2M x 4N); wave owns 128x64 output (8 mt x 4 nt frags of 16x16).
//
// BK=64, double-buffered: As/Bs[2][256*64] = 128 KB. One K-tile = 4 phases,
// ONE barrier per phase (trailing only):
//   phase: {ds_reads ks0,ks1} {stage quarter gloads} lgkmcnt(partial) ->
//          8 MFMA(ks0) -> lgkmcnt(0) -> 8 MFMA(ks1) -> s_barrier
// A wave starts MFMA as soon as ITS reads return; the LDS pipe keeps
// serving other waves -> LDS and MFMA overlap across waves instead of the
// CU-wide lockstep {LDS burst}{MFMA burst} the leading barrier caused.
//
// Correctness invariant: every phase's lgkmcnt(0) precedes its trailing
// barrier, so "all waves passed phase-p barrier" => "all phase-p reads
// complete". Stages only overwrite quarters whose LAST reads are in a
// strictly earlier phase:
//   A q0,q2 (rows 0-63,128-191) last read ph0 -> staged ph1
//   B (all quarters)            last read ph1 -> staged ph2
//   A q1,q3 (rows 64-127,192-255) last read ph2 -> staged ph3
// gload_lds writes land for tile kt+2; readers wait vmcnt at end of kt+1.
//
// vmcnt(8) once per K-tile (the 8 loads for kt+2 stay in flight); drains
// to 0 only at the tail. MFMA order is ks-outer: 8 independent accs
// between dependent re-accumulations.
//
// LDS swizzle (128 B rows): chunk p of row r stored at position p ^ (r&7).
// Linear LDS dest, inverse-permuted global source (full 128B-line
// coalescing); fragment read chunk (ks*4+quad) ^ (fm&7). 0 bank conflicts
// (verified by counter).
// ---------------------------------------------------------------------------
template <int EPI, typename OutT>
__global__ __launch_bounds__(512, 2) void gemm256_bt(
    const ushort_t* __restrict__ A, const ushort_t* __restrict__ B,
    OutT* __restrict__ C, const float* __restrict__ Mul,
    int M, int Ncol, int K) {
    __shared__ __align__(128) ushort_t As[2][256 * 64];   // 2 x 32 KB
    __shared__ __align__(128) ushort_t Bs[2][256 * 64];   // 2 x 32 KB

    const int t = threadIdx.x;
    const int wave = t >> 6, lane = t & 63;
    const int wm = wave >> 2, wn = wave & 3;            // 2 x 4 wave grid
    const int fm = lane & 15, quad = lane >> 4;

    // XCD-aware bijective swizzle (bm-inner mapping, lowest FETCH)
    const int nbn = Ncol >> 8;
    const int flat = blockIdx.y * gridDim.x + blockIdx.x;
    const int nwg = gridDim.x * gridDim.y;              // multiple of 8
    const int nid = (flat & 7) * (nwg >> 3) + (flat >> 3);
    const int bm = nid / nbn;
    const int bn = nid - bm * nbn;

    // staging: thread t -> row t>>3 (0..63 within a 64-row quarter),
    // phys chunk t&7; fetches global chunk (t&7)^(row&7).
    const int srow = t >> 3;
    const int schunk = ((t & 7) ^ (srow & 7)) << 3;     // elems
    const ushort_t* Ags = A + ((long)bm * 256 + srow) * K + schunk;
    const ushort_t* Bgs = B + ((long)bn * 256 + srow) * K + schunk;
    const int sdst = wave * 512;                        // ushorts (1KB/wave)

    // stage quarter q (rows q*64..q*64+63) of K-tile kt into buffer buf
#define STAGE_AQ(kt_, buf_, q_)                                          \
    GLOAD_LDS16(Ags + (long)(q_) * 64 * K + (long)(kt_) * 64,            \
                &As[buf_][(q_) * 4096 + sdst])
#define STAGE_BQ(kt_, buf_, q_)                                          \
    GLOAD_LDS16(Bgs + (long)(q_) * 64 * K + (long)(kt_) * 64,            \
                &Bs[buf_][(q_) * 4096 + sdst])

    // fragment addressing (ushort offsets; row stride 64 = 128 B)
    const int aoff = (wm * 128 + fm) * 64;
    const int boff = (wn * 64 + fm) * 64;
    const int cx0 = ((quad ^ (fm & 7)) << 3);           // ks=0 chunk
    const int cx1 = (((4 + quad) ^ (fm & 7)) << 3);     // ks=1 chunk

    floatx4 acc[8][4];
#pragma unroll
    for (int i = 0; i < 8; i++)
#pragma unroll
        for (int j = 0; j < 4; j++) acc[i][j] = (floatx4){0.f, 0.f, 0.f, 0.f};

    const int NKT = K >> 6;                              // 32
    // prologue: tiles 0 (buf0) and 1 (buf1), 16 loads/thread
#pragma unroll
    for (int q = 0; q < 4; q++) STAGE_AQ(0, 0, q);
#pragma unroll
    for (int q = 0; q < 4; q++) STAGE_BQ(0, 0, q);
#pragma unroll
    for (int q = 0; q < 4; q++) STAGE_AQ(1, 1, q);
#pragma unroll
    for (int q = 0; q < 4; q++) STAGE_BQ(1, 1, q);
    asm volatile("s_waitcnt vmcnt(8)" ::: "memory");     // tile 0 landed
    __builtin_amdgcn_s_barrier();

    for (int kt = 0; kt < NKT; ++kt) {
        const int cur = kt & 1;
        const ushort_t* Ab = &As[cur][0];
        const ushort_t* Bb = &Bs[cur][0];
        const bool st = (kt + 2 < NKT);                  // stage into cur

        bf16x8 a0[4][2], a1[4][2], bl[2][2], bh[2][2];

        // ------- phase 0: quadrant (mh0, nh0); reads a0 + bl -------
#pragma unroll
        for (int mt = 0; mt < 4; ++mt)
            a0[mt][0] = *(const bf16x8*)&Ab[aoff + mt * 1024 + cx0];
#pragma unroll
        for (int nt = 0; nt < 2; ++nt)
            bl[nt][0] = *(const bf16x8*)&Bb[boff + nt * 1024 + cx0];
#pragma unroll
        for (int mt = 0; mt < 4; ++mt)
            a0[mt][1] = *(const bf16x8*)&Ab[aoff + mt * 1024 + cx1];
#pragma unroll
        for (int nt = 0; nt < 2; ++nt)
            bl[nt][1] = *(const bf16x8*)&Bb[boff + nt * 1024 + cx1];
        asm volatile("s_waitcnt lgkmcnt(6)" ::: "memory");   // ks0 frags in
        __builtin_amdgcn_sched_barrier(0);
        __builtin_amdgcn_s_setprio(1);
#pragma unroll
        for (int mt = 0; mt < 4; ++mt)
#pragma unroll
            for (int nt = 0; nt < 2; ++nt)
                acc[mt][nt] = MFMA16(a0[mt][0], bl[nt][0], acc[mt][nt]);
        asm volatile("s_waitcnt lgkmcnt(0)" ::: "memory");
        __builtin_amdgcn_sched_barrier(0);
#pragma unroll
        for (int mt = 0; mt < 4; ++mt)
#pragma unroll
            for (int nt = 0; nt < 2; ++nt)
                acc[mt][nt] = MFMA16(a0[mt][1], bl[nt][1], acc[mt][nt]);
        __builtin_amdgcn_s_setprio(0);
        __builtin_amdgcn_s_barrier();

        // ------- phase 1: quadrant (mh0, nh1); reads bh; stage A q0,q2 ----
#pragma unroll
        for (int nt = 0; nt < 2; ++nt)
            bh[nt][0] = *(const bf16x8*)&Bb[boff + 2048 + nt * 1024 + cx0];
#pragma unroll
        for (int nt = 0; nt < 2; ++nt)
            bh[nt][1] = *(const bf16x8*)&Bb[boff + 2048 + nt * 1024 + cx1];
        if (st) { STAGE_AQ(kt + 2, cur, 0); STAGE_AQ(kt + 2, cur, 2); }
        asm volatile("s_waitcnt lgkmcnt(2)" ::: "memory");   // bh ks0 in
        __builtin_amdgcn_sched_barrier(0);
        __builtin_amdgcn_s_setprio(1);
#pragma unroll
        for (int mt = 0; mt < 4; ++mt)
#pragma unroll
            for (int nt = 0; nt < 2; ++nt)
                acc[mt][2 + nt] = MFMA16(a0[mt][0], bh[nt][0], acc[mt][2 + nt]);
        asm volatile("s_waitcnt lgkmcnt(0)" ::: "memory");
        __builtin_amdgcn_sched_barrier(0);
#pragma unroll
        for (int mt = 0; mt < 4; ++mt)
#pragma unroll
            for (int nt = 0; nt < 2; ++nt)
                acc[mt][2 + nt] = MFMA16(a0[mt][1], bh[nt][1], acc[mt][2 + nt]);
        __builtin_amdgcn_s_setprio(0);
        __builtin_amdgcn_s_barrier();

        // ------- phase 2: quadrant (mh1, nh1); reads a1; stage B all ------
#pragma unroll
        for (int mt = 0; mt < 4; ++mt)
            a1[mt][0] = *(const bf16x8*)&Ab[aoff + 4096 + mt * 1024 + cx0];
#pragma unroll
        for (int mt = 0; mt < 4; ++mt)
            a1[mt][1] = *(const bf16x8*)&Ab[aoff + 4096 + mt * 1024 + cx1];
        if (st) {
            STAGE_BQ(kt + 2, cur, 0); STAGE_BQ(kt + 2, cur, 1);
            STAGE_BQ(kt + 2, cur, 2); STAGE_BQ(kt + 2, cur, 3);
        }
        asm volatile("s_waitcnt lgkmcnt(4)" ::: "memory");   // a1 ks0 in
        __builtin_amdgcn_sched_barrier(0);
        __builtin_amdgcn_s_setprio(1);
#pragma unroll
        for (int mt = 0; mt < 4; ++mt)
#pragma unroll
            for (int nt = 0; nt < 2; ++nt)
                acc[4 + mt][2 + nt] = MFMA16(a1[mt][0], bh[nt][0], acc[4 + mt][2 + nt]);
        asm volatile("s_waitcnt lgkmcnt(0)" ::: "memory");
        __builtin_amdgcn_sched_barrier(0);
#pragma unroll
        for (int mt = 0; mt < 4; ++mt)
#pragma unroll
            for (int nt = 0; nt < 2; ++nt)
                acc[4 + mt][2 + nt] = MFMA16(a1[mt][1], bh[nt][1], acc[4 + mt][2 + nt]);
        __builtin_amdgcn_s_setprio(0);
        __builtin_amdgcn_s_barrier();

        // ------- phase 3: quadrant (mh1, nh0); no reads; stage A q1,q3 ----
        if (st) { STAGE_AQ(kt + 2, cur, 1); STAGE_AQ(kt + 2, cur, 3); }
        __builtin_amdgcn_sched_barrier(0);
        __builtin_amdgcn_s_setprio(1);
#pragma unroll
        for (int mt = 0; mt < 4; ++mt)
#pragma unroll
            for (int nt = 0; nt < 2; ++nt)
                acc[4 + mt][nt] = MFMA16(a1[mt][0], bl[nt][0], acc[4 + mt][nt]);
#pragma unroll
        for (int mt = 0; mt < 4; ++mt)
#pragma unroll
            for (int nt = 0; nt < 2; ++nt)
                acc[4 + mt][nt] = MFMA16(a1[mt][1], bl[nt][1], acc[4 + mt][nt]);
        __builtin_amdgcn_s_setprio(0);

        // ---- end of tile: counted wait (tile kt+1 landed; kt+2 in flight)
        if (kt + 2 < NKT) {
            asm volatile("s_waitcnt vmcnt(8)" ::: "memory");
        } else if (kt + 1 < NKT) {
            asm volatile("s_waitcnt vmcnt(0)" ::: "memory");
        }
        __builtin_amdgcn_s_barrier();
    }
#undef STAGE_AQ
#undef STAGE_BQ

    // epilogue
#pragma unroll
    for (int mt = 0; mt < 8; ++mt)
#pragma unroll
        for (int nt = 0; nt < 4; ++nt) {
            long col = (long)bn * 256 + wn * 64 + nt * 16 + fm;
#pragma unroll
            for (int r = 0; r < 4; ++r) {
                long row = (long)bm * 256 + wm * 128 + mt * 16 + quad * 4 + r;
                long idx = row * Ncol + col;
                float x = acc[mt][nt][r];
                float o;
                if (EPI == 0)      o = x / (1.f + expf(-x));          // silu
                else if (EPI == 1) o = x;                             // plain
                else               o = Mul[idx] / (1.f + expf(-x));   // gate
                store1(C + idx, o);
            }
        }
}

// ---------------------------------------------------------------------------
// MFMA contrib: contrib[h][b][d][e] = sum_n kd[n]*k[n][d]*v[n][e].
// Wave w owns d rows w*16..+16, loops 4 token-tiles of 64 (K accumulate).
// ---------------------------------------------------------------------------
__global__ __launch_bounds__(256) void attn_contrib_mfma(
    const ushort_t* __restrict__ qkv, float* __restrict__ contrib) {
    const int b = blockIdx.x, h = blockIdx.y;
    const float s = head_slope(h);
    __shared__ ushort_t kdT[64][72];   // [d][n]  k*kdecay, rows 144B
    __shared__ ushort_t vT[64][72];    // [e][n]
    const int t = threadIdx.x, wave = t >> 6, lane = t & 63;
    const int fm = lane & 15, quad = lane >> 4;
    const ushort_t* base = qkv + (long)(b * BLK) * QKVW + h * (3 * HDIM);

    floatx4 acc[4];
#pragma unroll
    for (int e = 0; e < 4; e++) acc[e] = (floatx4){0.f, 0.f, 0.f, 0.f};

    const int sn = t & 63;             // token within tile
    const int sc0 = t >> 6;            // chunk 0..3 (+4)

    for (int tt = 0; tt < 4; tt++) {
        __syncthreads();
        int tok = tt * 64 + sn;
        float kd = expf(-s * (float)(BLK - 1 - tok));
#pragma unroll
        for (int cc = 0; cc < 2; cc++) {
            int c = sc0 + cc * 4;
            bf16x8 k8 = *(const bf16x8*)(base + (long)tok * QKVW + HDIM + c * 8);
            bf16x8 v8 = *(const bf16x8*)(base + (long)tok * QKVW + 2 * HDIM + c * 8);
#pragma unroll
            for (int j = 0; j < 8; j++) {
                kdT[c * 8 + j][sn] = f2bf(bf2f((ushort_t)k8[j]) * kd);
                vT[c * 8 + j][sn]  = (ushort_t)v8[j];
            }
        }
        __syncthreads();
#pragma unroll
        for (int kh = 0; kh < 2; kh++) {
            bf16x8 a = *(const bf16x8*)&kdT[wave * 16 + fm][kh * 32 + quad * 8];
#pragma unroll
            for (int e = 0; e < 4; e++) {
                bf16x8 bb = *(const bf16x8*)&vT[e * 16 + fm][kh * 32 + quad * 8];
                acc[e] = MFMA16(a, bb, acc[e]);
            }
        }
    }
    float* outp = contrib + ((long)(h * NBLK + b)) * 4096;
#pragma unroll
    for (int e = 0; e < 4; e++)
#pragma unroll
        for (int r = 0; r < 4; r++) {
            int d = wave * 16 + quad * 4 + r;
            outp[d * 64 + e * 16 + fm] = acc[e][r];
        }
}

// ---------------------------------------------------------------------------
// Sequential decay scan over blocks (in-place safe).
// ---------------------------------------------------------------------------
__global__ __launch_bounds__(256) void attn_scan(
    const float* __restrict__ kv0, const float* __restrict__ contrib,
    float* __restrict__ states) {
    const int h = blockIdx.x, t = threadIdx.x;
    const float s  = head_slope(h);
    const float bd = expf(-s * (float)BLK);
    float st[16], c[16];
    const float* kvp = kv0 + (long)h * 4096;
#pragma unroll
    for (int i = 0; i < 16; i++) st[i] = kvp[t + 256 * i];
    for (int b = 0; b < NBLK; b++) {
        const float* cp = contrib + ((long)(h * NBLK + b)) * 4096;
        float* sp = states + ((long)(h * NBLK + b)) * 4096;
#pragma unroll
        for (int i = 0; i < 16; i++) c[i] = cp[t + 256 * i];
#pragma unroll
        for (int i = 0; i < 16; i++) sp[t + 256 * i] = st[i];
#pragma unroll
        for (int i = 0; i < 16; i++) st[i] = bd * st[i] + c[i];
    }
}

// ---------------------------------------------------------------------------
// MFMA attention core per (h,b):
//   out = diag(qdec)*(q @ state) + ((q@k^T) .* decay) @ v
// Wave w owns q rows w*64..+64. S computed transposed (A=k, B=q) so the
// decayed tile stores to Sw[m][n] as ushort4 rows; then intra A=Sw, B=vT.
// ---------------------------------------------------------------------------
__global__ __launch_bounds__(256) void attn_core_mfma(
    const ushort_t* __restrict__ qkv, const float* __restrict__ states,
    float* __restrict__ hidden) {
    const int b = blockIdx.x, h = blockIdx.y;
    const float s = head_slope(h);
    __shared__ ushort_t Sw[4][64][72];   // per-wave S tile; Sw[0] = stT first
    __shared__ ushort_t kS[64 * 64];     // k tile [n][d], 128B rows, swizzled
    __shared__ ushort_t vT[64][72];      // v tile [e][n]
    __shared__ float dtab[257];          // exp(-s*delta)
    __shared__ float etab[64];           // exp(+s*j)
    const int t = threadIdx.x, wave = t >> 6, lane = t & 63;
    const int fm = lane & 15, quad = lane >> 4;
    const ushort_t* base = qkv + (long)(b * BLK) * QKVW + h * (3 * HDIM);

    dtab[t] = expf(-s * (float)t);
    if (t == 0) dtab[256] = expf(-s * 256.f);
    if (t < 64) etab[t] = expf(s * (float)t);

    {   // stT = Sw[0]: [e][d] <- states (bf16)
        const float* sp = states + ((long)(h * NBLK + b)) * 4096;
#pragma unroll
        for (int i = 0; i < 4; i++) {
            int idx = t + 256 * i;
            int d = idx >> 4, e4 = (idx & 15) * 4;
            float4 st4 = *(const float4*)(sp + d * 64 + e4);
            Sw[0][e4 + 0][d] = f2bf(st4.x);
            Sw[0][e4 + 1][d] = f2bf(st4.y);
            Sw[0][e4 + 2][d] = f2bf(st4.z);
            Sw[0][e4 + 3][d] = f2bf(st4.w);
        }
    }

    // q fragments from global (read once)
    bf16x8 aq[4][2];
#pragma unroll
    for (int mt = 0; mt < 4; mt++)
#pragma unroll
        for (int kh = 0; kh < 2; kh++)
            aq[mt][kh] = *(const bf16x8*)(base +
                (long)(wave * 64 + mt * 16 + fm) * QKVW + kh * 32 + quad * 8);

    __syncthreads();

    // inter = q @ state, then row-scale by qdecay
    floatx4 acc[4][4];
#pragma unroll
    for (int i = 0; i < 4; i++)
#pragma unroll
        for (int j = 0; j < 4; j++) acc[i][j] = (floatx4){0.f, 0.f, 0.f, 0.f};
#pragma unroll
    for (int kh = 0; kh < 2; kh++)
#pragma unroll
        for (int et = 0; et < 4; et++) {
            bf16x8 bst = *(const bf16x8*)&Sw[0][et * 16 + fm][kh * 32 + quad * 8];
#pragma unroll
            for (int mt = 0; mt < 4; mt++)
                acc[mt][et] = MFMA16(aq[mt][kh], bst, acc[mt][et]);
        }
#pragma unroll
    for (int mt = 0; mt < 4; mt++)
#pragma unroll
        for (int r = 0; r < 4; r++) {
            float qd = dtab[wave * 64 + mt * 16 + quad * 4 + r + 1];
#pragma unroll
            for (int et = 0; et < 4; et++) acc[mt][et][r] *= qd;
        }

    // intra over k-tiles (uniform loop; wave computes only nt <= wave)
    const int sn = t & 63, sc0 = t >> 6;
    for (int nt = 0; nt < 4; nt++) {
        __syncthreads();   // prior reads of kS/vT/stT done before restage
        // stage kS via global_load_lds, chunk-swizzled (pos p holds p^(n&7))
#pragma unroll
        for (int i = 0; i < 2; i++) {
            int row = i * 32 + wave * 8 + (lane >> 3);
            const ushort_t* g = base + (long)(nt * 64 + row) * QKVW + HDIM +
                                (((lane & 7) ^ (lane >> 3)) * 8);
            GLOAD_LDS16(g, &kS[(i * 32 + wave * 8) * 64]);
        }
        // stage vT tile [e][n]
#pragma unroll
        for (int cc = 0; cc < 2; cc++) {
            int c = sc0 + cc * 4;
            bf16x8 v8 = *(const bf16x8*)(base + (long)(nt * 64 + sn) * QKVW +
                                         2 * HDIM + c * 8);
#pragma unroll
            for (int j = 0; j < 8; j++) vT[c * 8 + j][sn] = (ushort_t)v8[j];
        }
        __syncthreads();

        if (nt <= wave) {
            // S^T = k @ q^T : C row = n, col = m
            floatx4 sacc[4][4];
#pragma unroll
            for (int i = 0; i < 4; i++)
#pragma unroll
                for (int j = 0; j < 4; j++) sacc[i][j] = (floatx4){0.f, 0.f, 0.f, 0.f};
#pragma unroll
            for (int kh = 0; kh < 2; kh++) {
                bf16x8 ak[4];
#pragma unroll
                for (int snt = 0; snt < 4; snt++) {
                    int n = snt * 16 + fm;
                    int pos = (kh * 4 + quad) ^ (n & 7);
                    ak[snt] = *(const bf16x8*)&kS[n * 64 + pos * 8];
                }
#pragma unroll
                for (int snt = 0; snt < 4; snt++)
#pragma unroll
                    for (int smt = 0; smt < 4; smt++)
                        sacc[snt][smt] = MFMA16(ak[snt], aq[smt][kh], sacc[snt][smt]);
            }
            // decay + mask + bf16, store Sw[wave][m][n] (ushort4 rows)
#pragma unroll
            for (int snt = 0; snt < 4; snt++)
#pragma unroll
                for (int smt = 0; smt < 4; smt++) {
                    int mloc = smt * 16 + fm;              // 0..63 in wave rows
                    float rf = dtab[wave * 64 + mloc - nt * 64];
                    ushortx4 o;
#pragma unroll
                    for (int r = 0; r < 4; r++) {
                        int nloc = snt * 16 + quad * 4 + r;
                        float v = sacc[snt][smt][r] * rf * etab[nloc];
                        if (nt == wave && mloc < nloc) v = 0.f;
                        o[r] = f2bf(v);
                    }
                    *(ushortx4*)&Sw[wave][mloc][snt * 16 + quad * 4] = o;
                }
            // intra: acc += S @ v  (A = Sw rows m, B = vT rows e)
#pragma unroll
            for (int kh = 0; kh < 2; kh++) {
                bf16x8 as[4];
#pragma unroll
                for (int mt = 0; mt < 4; mt++)
                    as[mt] = *(const bf16x8*)&Sw[wave][mt * 16 + fm][kh * 32 + quad * 8];
#pragma unroll
                for (int et = 0; et < 4; et++) {
                    bf16x8 bv = *(const bf16x8*)&vT[et * 16 + fm][kh * 32 + quad * 8];
#pragma unroll
                    for (int mt = 0; mt < 4; mt++)
                        acc[mt][et] = MFMA16(as[mt], bv, acc[mt][et]);
                }
            }
        }
    }

    // write hidden[token][h*64+e] (coalesced 64B per quad)
#pragma unroll
    for (int mt = 0; mt < 4; mt++)
#pragma unroll
        for (int r = 0; r < 4; r++) {
            long tok = (long)b * BLK + wave * 64 + mt * 16 + quad * 4 + r;
            float* hp = hidden + tok * HIDDEN + h * HDIM;
#pragma unroll
            for (int et = 0; et < 4; et++)
                hp[et * 16 + fm] = acc[mt][et][r];
        }
}

// ---------------------------------------------------------------------------
// RMSNorm over rows (in place). grid NTOK, 256 threads.
// ---------------------------------------------------------------------------
__global__ __launch_bounds__(256) void rmsnorm_rows(
    float* __restrict__ hidden, const float* __restrict__ w) {
    const int row = blockIdx.x, t = threadIdx.x;
    float* hp = hidden + (long)row * HIDDEN;
    float4 a = *(const float4*)(hp + (t << 2));
    float4 b = *(const float4*)(hp + 1024 + (t << 2));
    float ss = a.x * a.x + a.y * a.y + a.z * a.z + a.w * a.w +
               b.x * b.x + b.y * b.y + b.z * b.z + b.w * b.w;
#pragma unroll
    for (int off = 32; off > 0; off >>= 1) ss += __shfl_down(ss, off);
    __shared__ float red[4];
    if ((t & 63) == 0) red[t >> 6] = ss;
    __syncthreads();
    float tot = red[0] + red[1] + red[2] + red[3];
    float scale = rsqrtf(tot * (1.f / HIDDEN) + 1e-5f);
    float4 wa = *(const float4*)(w + (t << 2));
    float4 wb = *(const float4*)(w + 1024 + (t << 2));
    a.x *= scale * wa.x; a.y *= scale * wa.y; a.z *= scale * wa.z; a.w *= scale * wa.w;
    b.x *= scale * wb.x; b.y *= scale * wb.y; b.z *= scale * wb.z; b.w *= scale * wb.w;
    *(float4*)(hp + (t << 2)) = a;
    *(float4*)(hp + 1024 + (t << 2)) = b;
}

// ---------------------------------------------------------------------------
extern "C" void kernel_launch(void* const* d_in, const int* in_sizes, int n_in,
                              void* d_out, int out_size, void* d_ws, size_t ws_size,
                              hipStream_t stream) {
    (void)in_sizes; (void)n_in; (void)out_size; (void)ws_size;
    const float* hs   = (const float*)d_in[0];
    const float* kv0  = (const float*)d_in[1];
    const float* Wqkv = (const float*)d_in[2];
    const float* Wg   = (const float*)d_in[3];
    const float* Wo   = (const float*)d_in[4];
    const float* nw   = (const float*)d_in[5];
    float* out = (float*)d_out;

    ushort_t* hs_h   = (ushort_t*)d_ws;
    ushort_t* wqkv_h = hs_h + (size_t)NTOK * HIDDEN;
    ushort_t* wg_h   = wqkv_h + (size_t)QKVW * HIDDEN;
    ushort_t* wo_h   = wg_h + (size_t)HIDDEN * HIDDEN;
    ushort_t* qkv_h  = wo_h + (size_t)HIDDEN * HIDDEN;
    float*    cs     = (float*)(qkv_h + (size_t)NTOK * QKVW);
    ushort_t* gated  = qkv_h;                    // reuse after attention

    cvt_bf16<<<(NTOK * HIDDEN / 8 + 255) / 256, 256, 0, stream>>>(
        hs, hs_h, NTOK * HIDDEN / 8);
    cvt_bf16<<<(QKVW * HIDDEN / 8 + 255) / 256, 256, 0, stream>>>(
        Wqkv, wqkv_h, QKVW * HIDDEN / 8);
    cvt_bf16<<<(HIDDEN * HIDDEN / 8 + 255) / 256, 256, 0, stream>>>(
        Wg, wg_h, HIDDEN * HIDDEN / 8);
    cvt_bf16<<<(HIDDEN * HIDDEN / 8 + 255) / 256, 256, 0, stream>>>(
        Wo, wo_h, HIDDEN * HIDDEN / 8);

    gemm256_bt<0, ushort_t><<<dim3(QKVW / 256, NTOK / 256), 512, 0, stream>>>(
        hs_h, wqkv_h, qkv_h, nullptr, NTOK, QKVW, HIDDEN);
    attn_contrib_mfma<<<dim3(NBLK, NHEAD), 256, 0, stream>>>(qkv_h, cs);
    attn_scan<<<NHEAD, 256, 0, stream>>>(kv0, cs, cs);
    attn_core_mfma<<<dim3(NBLK, NHEAD), 256, 0, stream>>>(qkv_h, cs, out);
    rmsnorm_rows<<<NTOK, 256, 0, stream>>>(out, nw);
    gemm256_bt<2, ushort_t><<<dim3(HIDDEN / 256, NTOK / 256), 512, 0, stream>>>(
        hs_h, wg_h, gated, out, NTOK, HIDDEN, HIDDEN);
    gemm256_bt<1, float><<<dim3(HIDDEN / 256, NTOK / 256), 512, 0, stream>>>(
        gated, wo_h, out, nullptr, NTOK, HIDDEN, HIDDEN);
}

// Round 5
// 653.183 us; speedup vs baseline: 1.0935x; 1.0935x over previous
//
#include <hip/hip_runtime.h>

// Problem constants (fixed by reference)
#define NTOK   8192
#define HIDDEN 2048
#define NHEAD  32
#define HDIM   64
#define BLK    256
#define NBLK   32          // NTOK / BLK
#define QKVW   6144        // 3 * HIDDEN

typedef unsigned short ushort_t;
typedef __attribute__((ext_vector_type(8))) short bf16x8;   // 8 bf16 = 4 VGPRs
typedef __attribute__((ext_vector_type(4))) float floatx4;  // MFMA C/D
typedef __attribute__((ext_vector_type(4))) unsigned short ushortx4;

#define MFMA16(a, b, c) __builtin_amdgcn_mfma_f32_16x16x32_bf16(a, b, c, 0, 0, 0)

// slope[h] = 2^(-0.25*(h+1)) * (1 - 0/79 + 1e-5)
__device__ __forceinline__ float head_slope(int h) {
    return exp2f(-0.25f * (float)(h + 1)) * 1.00001f;
}

__device__ __forceinline__ ushort_t f2bf(float x) {
    unsigned int u = __float_as_uint(x);
    unsigned int r = (u + 0x7FFFu + ((u >> 16) & 1u)) >> 16;   // RNE
    return (ushort_t)r;
}
__device__ __forceinline__ float bf2f(ushort_t x) {
    return __uint_as_float(((unsigned int)x) << 16);
}
__device__ __forceinline__ void store1(float* p, float v) { *p = v; }
__device__ __forceinline__ void store1(ushort_t* p, float v) { *p = f2bf(v); }

// async global->LDS, 16B per lane (lds dest = wave-uniform base + lane*16;
// global source is per-lane)
#define GLOAD_LDS16(g, l)                                              \
    __builtin_amdgcn_global_load_lds(                                  \
        (const __attribute__((address_space(1))) void*)(g),            \
        (__attribute__((address_space(3))) void*)(l), 16, 0, 0)

// ---------------------------------------------------------------------------
// fp32 -> bf16 convert, 8 elems/thread.
// ---------------------------------------------------------------------------
__global__ __launch_bounds__(256) void cvt_bf16(
    const float* __restrict__ in, ushort_t* __restrict__ out, int n8) {
    int i = blockIdx.x * 256 + threadIdx.x;
    if (i >= n8) return;
    long base = (long)i * 8;
    float4 a = *(const float4*)(in + base);
    float4 b = *(const float4*)(in + base + 4);
    ushort4 u0 = {f2bf(a.x), f2bf(a.y), f2bf(a.z), f2bf(a.w)};
    ushort4 u1 = {f2bf(b.x), f2bf(b.y), f2bf(b.z), f2bf(b.w)};
    *(ushort4*)(out + base) = u0;
    *(ushort4*)(out + base + 4) = u1;
}

// ---------------------------------------------------------------------------
// 256x256-tile bf16 MFMA GEMM, 8-phase (m201) schedule — round-3 structure
// restored verbatim (empirical best: 244.8 us QKV, MfmaUtil 36%), plus the
// m201 "optional lgkmcnt(8) pre-drain" before the 12-read phase's barrier.
//
// BK=64, double-buffered: As/Bs[2][256*64] = 128 KB. One K-tile = 4 phases;
// each phase: {ds_reads (12/4/8/0)} {stage quarter gloads} [lgkm predrain]
// s_barrier; lgkmcnt(0); sched_barrier; setprio(1); 16 MFMA; setprio(0);
// s_barrier.   (Two barriers per phase — removing the leading one was
// measured WORSE (round 4: 36%->32%); do not "optimize" it away.)
//
// Staging recycles the CURRENT buffer (tile kt+2 has same parity as kt),
// quarter-by-quarter right after its last LDS read:
//   A q0,q2 (mh0 rows) last read ph0 -> staged ph1
//   B (all quarters)   last read ph1 -> staged ph2
//   A q1,q3 (mh1 rows) last read ph2 -> staged ph3
// Safety: each wave's lgkmcnt(0) precedes its phase-end barrier, so passing
// that barrier implies ALL waves' reads of this phase completed; stages are
// issued only after the relevant phase-end barrier.
//
// vmcnt(8) once per K-tile (8 newer loads = tile kt+2 stay in flight);
// drains to 0 only at the tail tile.
//
// LDS swizzle (128 B rows): chunk p of row r stored at position p ^ (r&7).
// Linear LDS dest, inverse-permuted global source (full 128B-line
// coalescing); fragment read chunk (ks*4+quad) ^ (fm&7). 0 bank conflicts
// (verified by counter).
// ---------------------------------------------------------------------------
template <int EPI, typename OutT>
__global__ __launch_bounds__(512, 2) void gemm256_bt(
    const ushort_t* __restrict__ A, const ushort_t* __restrict__ B,
    OutT* __restrict__ C, const float* __restrict__ Mul,
    int M, int Ncol, int K) {
    __shared__ __align__(128) ushort_t As[2][256 * 64];   // 2 x 32 KB
    __shared__ __align__(128) ushort_t Bs[2][256 * 64];   // 2 x 32 KB

    const int t = threadIdx.x;
    const int wave = t >> 6, lane = t & 63;
    const int wm = wave >> 2, wn = wave & 3;            // 2 x 4 wave grid
    const int fm = lane & 15, quad = lane >> 4;

    // XCD-aware bijective swizzle (bm-inner; round-1 mapping, lowest FETCH)
    const int nbn = Ncol >> 8;
    const int flat = blockIdx.y * gridDim.x + blockIdx.x;
    const int nwg = gridDim.x * gridDim.y;              // multiple of 8
    const int nid = (flat & 7) * (nwg >> 3) + (flat >> 3);
    const int bm = nid / nbn;
    const int bn = nid - bm * nbn;

    // staging: thread t -> row t>>3 (0..63 within a 64-row quarter),
    // phys chunk t&7; fetches global chunk (t&7)^(row&7).
    const int srow = t >> 3;
    const int schunk = ((t & 7) ^ (srow & 7)) << 3;     // elems
    const ushort_t* Ags = A + ((long)bm * 256 + srow) * K + schunk;
    const ushort_t* Bgs = B + ((long)bn * 256 + srow) * K + schunk;
    const int sdst = wave * 512;                        // ushorts (1KB/wave)

    // stage quarter q (rows q*64..q*64+63) of K-tile kt into buffer buf
#define STAGE_AQ(kt_, buf_, q_)                                          \
    GLOAD_LDS16(Ags + (long)(q_) * 64 * K + (long)(kt_) * 64,            \
                &As[buf_][(q_) * 4096 + sdst])
#define STAGE_BQ(kt_, buf_, q_)                                          \
    GLOAD_LDS16(Bgs + (long)(q_) * 64 * K + (long)(kt_) * 64,            \
                &Bs[buf_][(q_) * 4096 + sdst])

    // fragment addressing (ushort offsets; row stride 64 = 128 B)
    const int aoff = (wm * 128 + fm) * 64;
    const int boff = (wn * 64 + fm) * 64;
    const int cx0 = ((quad ^ (fm & 7)) << 3);           // ks=0 chunk
    const int cx1 = (((4 + quad) ^ (fm & 7)) << 3);     // ks=1 chunk

    floatx4 acc[8][4];
#pragma unroll
    for (int i = 0; i < 8; i++)
#pragma unroll
        for (int j = 0; j < 4; j++) acc[i][j] = (floatx4){0.f, 0.f, 0.f, 0.f};

    const int NKT = K >> 6;                              // 32
    // prologue: tiles 0 (buf0) and 1 (buf1), 16 loads/thread
#pragma unroll
    for (int q = 0; q < 4; q++) STAGE_AQ(0, 0, q);
#pragma unroll
    for (int q = 0; q < 4; q++) STAGE_BQ(0, 0, q);
#pragma unroll
    for (int q = 0; q < 4; q++) STAGE_AQ(1, 1, q);
#pragma unroll
    for (int q = 0; q < 4; q++) STAGE_BQ(1, 1, q);
    asm volatile("s_waitcnt vmcnt(8)" ::: "memory");     // tile 0 landed
    __builtin_amdgcn_s_barrier();

    for (int kt = 0; kt < NKT; ++kt) {
        const int cur = kt & 1;
        const ushort_t* Ab = &As[cur][0];
        const ushort_t* Bb = &Bs[cur][0];
        const bool st = (kt + 2 < NKT);                  // stage into cur

        bf16x8 a0[4][2], a1[4][2], bl[2][2], bh[2][2];

        // ---------------- phase 0: quadrant (mh0, nh0) ----------------
#pragma unroll
        for (int mt = 0; mt < 4; ++mt) {
            a0[mt][0] = *(const bf16x8*)&Ab[aoff + mt * 1024 + cx0];
            a0[mt][1] = *(const bf16x8*)&Ab[aoff + mt * 1024 + cx1];
        }
#pragma unroll
        for (int nt = 0; nt < 2; ++nt) {
            bl[nt][0] = *(const bf16x8*)&Bb[boff + nt * 1024 + cx0];
            bl[nt][1] = *(const bf16x8*)&Bb[boff + nt * 1024 + cx1];
        }
        asm volatile("s_waitcnt lgkmcnt(8)" ::: "memory");   // m201 pre-drain
        __builtin_amdgcn_s_barrier();
        asm volatile("s_waitcnt lgkmcnt(0)" ::: "memory");
        __builtin_amdgcn_sched_barrier(0);
        __builtin_amdgcn_s_setprio(1);
#pragma unroll
        for (int mt = 0; mt < 4; ++mt)
#pragma unroll
            for (int nt = 0; nt < 2; ++nt) {
                acc[mt][nt] = MFMA16(a0[mt][0], bl[nt][0], acc[mt][nt]);
                acc[mt][nt] = MFMA16(a0[mt][1], bl[nt][1], acc[mt][nt]);
            }
        __builtin_amdgcn_s_setprio(0);
        __builtin_amdgcn_s_barrier();

        // ---------------- phase 1: quadrant (mh0, nh1) ----------------
#pragma unroll
        for (int nt = 0; nt < 2; ++nt) {
            bh[nt][0] = *(const bf16x8*)&Bb[boff + 2048 + nt * 1024 + cx0];
            bh[nt][1] = *(const bf16x8*)&Bb[boff + 2048 + nt * 1024 + cx1];
        }
        if (st) { STAGE_AQ(kt + 2, cur, 0); STAGE_AQ(kt + 2, cur, 2); }
        __builtin_amdgcn_s_barrier();
        asm volatile("s_waitcnt lgkmcnt(0)" ::: "memory");
        __builtin_amdgcn_sched_barrier(0);
        __builtin_amdgcn_s_setprio(1);
#pragma unroll
        for (int mt = 0; mt < 4; ++mt)
#pragma unroll
            for (int nt = 0; nt < 2; ++nt) {
                acc[mt][2 + nt] = MFMA16(a0[mt][0], bh[nt][0], acc[mt][2 + nt]);
                acc[mt][2 + nt] = MFMA16(a0[mt][1], bh[nt][1], acc[mt][2 + nt]);
            }
        __builtin_amdgcn_s_setprio(0);
        __builtin_amdgcn_s_barrier();

        // ---------------- phase 2: quadrant (mh1, nh1) ----------------
#pragma unroll
        for (int mt = 0; mt < 4; ++mt) {
            a1[mt][0] = *(const bf16x8*)&Ab[aoff + 4096 + mt * 1024 + cx0];
            a1[mt][1] = *(const bf16x8*)&Ab[aoff + 4096 + mt * 1024 + cx1];
        }
        if (st) {
            STAGE_BQ(kt + 2, cur, 0); STAGE_BQ(kt + 2, cur, 1);
            STAGE_BQ(kt + 2, cur, 2); STAGE_BQ(kt + 2, cur, 3);
        }
        __builtin_amdgcn_s_barrier();
        asm volatile("s_waitcnt lgkmcnt(0)" ::: "memory");
        __builtin_amdgcn_sched_barrier(0);
        __builtin_amdgcn_s_setprio(1);
#pragma unroll
        for (int mt = 0; mt < 4; ++mt)
#pragma unroll
            for (int nt = 0; nt < 2; ++nt) {
                acc[4 + mt][2 + nt] = MFMA16(a1[mt][0], bh[nt][0], acc[4 + mt][2 + nt]);
                acc[4 + mt][2 + nt] = MFMA16(a1[mt][1], bh[nt][1], acc[4 + mt][2 + nt]);
            }
        __builtin_amdgcn_s_setprio(0);
        __builtin_amdgcn_s_barrier();

        // ---------------- phase 3: quadrant (mh1, nh0) ----------------
        if (st) { STAGE_AQ(kt + 2, cur, 1); STAGE_AQ(kt + 2, cur, 3); }
        __builtin_amdgcn_s_barrier();
        __builtin_amdgcn_sched_barrier(0);
        __builtin_amdgcn_s_setprio(1);
#pragma unroll
        for (int mt = 0; mt < 4; ++mt)
#pragma unroll
            for (int nt = 0; nt < 2; ++nt) {
                acc[4 + mt][nt] = MFMA16(a1[mt][0], bl[nt][0], acc[4 + mt][nt]);
                acc[4 + mt][nt] = MFMA16(a1[mt][1], bl[nt][1], acc[4 + mt][nt]);
            }
        __builtin_amdgcn_s_setprio(0);

        // ---- end of tile: counted wait (tile kt+1 landed; kt+2 in flight)
        if (kt + 2 < NKT) {
            asm volatile("s_waitcnt vmcnt(8)" ::: "memory");
        } else if (kt + 1 < NKT) {
            asm volatile("s_waitcnt vmcnt(0)" ::: "memory");
        }
        __builtin_amdgcn_s_barrier();
    }
#undef STAGE_AQ
#undef STAGE_BQ

    // epilogue
#pragma unroll
    for (int mt = 0; mt < 8; ++mt)
#pragma unroll
        for (int nt = 0; nt < 4; ++nt) {
            long col = (long)bn * 256 + wn * 64 + nt * 16 + fm;
#pragma unroll
            for (int r = 0; r < 4; ++r) {
                long row = (long)bm * 256 + wm * 128 + mt * 16 + quad * 4 + r;
                long idx = row * Ncol + col;
                float x = acc[mt][nt][r];
                float o;
                if (EPI == 0)      o = x / (1.f + expf(-x));          // silu
                else if (EPI == 1) o = x;                             // plain
                else               o = Mul[idx] / (1.f + expf(-x));   // gate
                store1(C + idx, o);
            }
        }
}

// ---------------------------------------------------------------------------
// MFMA contrib: contrib[h][b][d][e] = sum_n kd[n]*k[n][d]*v[n][e].
// Wave w owns d rows w*16..+16, loops 4 token-tiles of 64 (K accumulate).
// ---------------------------------------------------------------------------
__global__ __launch_bounds__(256) void attn_contrib_mfma(
    const ushort_t* __restrict__ qkv, float* __restrict__ contrib) {
    const int b = blockIdx.x, h = blockIdx.y;
    const float s = head_slope(h);
    __shared__ ushort_t kdT[64][72];   // [d][n]  k*kdecay, rows 144B
    __shared__ ushort_t vT[64][72];    // [e][n]
    const int t = threadIdx.x, wave = t >> 6, lane = t & 63;
    const int fm = lane & 15, quad = lane >> 4;
    const ushort_t* base = qkv + (long)(b * BLK) * QKVW + h * (3 * HDIM);

    floatx4 acc[4];
#pragma unroll
    for (int e = 0; e < 4; e++) acc[e] = (floatx4){0.f, 0.f, 0.f, 0.f};

    const int sn = t & 63;             // token within tile
    const int sc0 = t >> 6;            // chunk 0..3 (+4)

    for (int tt = 0; tt < 4; tt++) {
        __syncthreads();
        int tok = tt * 64 + sn;
        float kd = expf(-s * (float)(BLK - 1 - tok));
#pragma unroll
        for (int cc = 0; cc < 2; cc++) {
            int c = sc0 + cc * 4;
            bf16x8 k8 = *(const bf16x8*)(base + (long)tok * QKVW + HDIM + c * 8);
            bf16x8 v8 = *(const bf16x8*)(base + (long)tok * QKVW + 2 * HDIM + c * 8);
#pragma unroll
            for (int j = 0; j < 8; j++) {
                kdT[c * 8 + j][sn] = f2bf(bf2f((ushort_t)k8[j]) * kd);
                vT[c * 8 + j][sn]  = (ushort_t)v8[j];
            }
        }
        __syncthreads();
#pragma unroll
        for (int kh = 0; kh < 2; kh++) {
            bf16x8 a = *(const bf16x8*)&kdT[wave * 16 + fm][kh * 32 + quad * 8];
#pragma unroll
            for (int e = 0; e < 4; e++) {
                bf16x8 bb = *(const bf16x8*)&vT[e * 16 + fm][kh * 32 + quad * 8];
                acc[e] = MFMA16(a, bb, acc[e]);
            }
        }
    }
    float* outp = contrib + ((long)(h * NBLK + b)) * 4096;
#pragma unroll
    for (int e = 0; e < 4; e++)
#pragma unroll
        for (int r = 0; r < 4; r++) {
            int d = wave * 16 + quad * 4 + r;
            outp[d * 64 + e * 16 + fm] = acc[e][r];
        }
}

// ---------------------------------------------------------------------------
// Sequential decay scan over blocks (in-place safe).
// Parallelized: grid (NHEAD, 4); each block owns a 1024-float segment of the
// 4096-elem state; float4 per thread. Scan dependency is only over b.
// ---------------------------------------------------------------------------
__global__ __launch_bounds__(256) void attn_scan(
    const float* __restrict__ kv0, const float* __restrict__ contrib,
    float* __restrict__ states) {
    const int h = blockIdx.x, seg = blockIdx.y, t = threadIdx.x;
    const float s  = head_slope(h);
    const float bd = expf(-s * (float)BLK);
    const int off = seg * 1024 + t * 4;
    float4 st = *(const float4*)(kv0 + (long)h * 4096 + off);
    for (int b = 0; b < NBLK; b++) {
        const long base = ((long)(h * NBLK + b)) * 4096 + off;
        float4 c = *(const float4*)(contrib + base);
        *(float4*)(states + base) = st;
        st.x = bd * st.x + c.x;
        st.y = bd * st.y + c.y;
        st.z = bd * st.z + c.z;
        st.w = bd * st.w + c.w;
    }
}

// ---------------------------------------------------------------------------
// MFMA attention core per (h,b):
//   out = diag(qdec)*(q @ state) + ((q@k^T) .* decay) @ v
// Wave w owns q rows w*64..+64. S computed transposed (A=k, B=q) so the
// decayed tile stores to Sw[m][n] as ushort4 rows; then intra A=Sw, B=vT.
// ---------------------------------------------------------------------------
__global__ __launch_bounds__(256) void attn_core_mfma(
    const ushort_t* __restrict__ qkv, const float* __restrict__ states,
    float* __restrict__ hidden) {
    const int b = blockIdx.x, h = blockIdx.y;
    const float s = head_slope(h);
    __shared__ ushort_t Sw[4][64][72];   // per-wave S tile; Sw[0] = stT first
    __shared__ ushort_t kS[64 * 64];     // k tile [n][d], 128B rows, swizzled
    __shared__ ushort_t vT[64][72];      // v tile [e][n]
    __shared__ float dtab[257];          // exp(-s*delta)
    __shared__ float etab[64];           // exp(+s*j)
    const int t = threadIdx.x, wave = t >> 6, lane = t & 63;
    const int fm = lane & 15, quad = lane >> 4;
    const ushort_t* base = qkv + (long)(b * BLK) * QKVW + h * (3 * HDIM);

    dtab[t] = expf(-s * (float)t);
    if (t == 0) dtab[256] = expf(-s * 256.f);
    if (t < 64) etab[t] = expf(s * (float)t);

    {   // stT = Sw[0]: [e][d] <- states (bf16)
        const float* sp = states + ((long)(h * NBLK + b)) * 4096;
#pragma unroll
        for (int i = 0; i < 4; i++) {
            int idx = t + 256 * i;
            int d = idx >> 4, e4 = (idx & 15) * 4;
            float4 st4 = *(const float4*)(sp + d * 64 + e4);
            Sw[0][e4 + 0][d] = f2bf(st4.x);
            Sw[0][e4 + 1][d] = f2bf(st4.y);
            Sw[0][e4 + 2][d] = f2bf(st4.z);
            Sw[0][e4 + 3][d] = f2bf(st4.w);
        }
    }

    // q fragments from global (read once)
    bf16x8 aq[4][2];
#pragma unroll
    for (int mt = 0; mt < 4; mt++)
#pragma unroll
        for (int kh = 0; kh < 2; kh++)
            aq[mt][kh] = *(const bf16x8*)(base +
                (long)(wave * 64 + mt * 16 + fm) * QKVW + kh * 32 + quad * 8);

    __syncthreads();

    // inter = q @ state, then row-scale by qdecay
    floatx4 acc[4][4];
#pragma unroll
    for (int i = 0; i < 4; i++)
#pragma unroll
        for (int j = 0; j < 4; j++) acc[i][j] = (floatx4){0.f, 0.f, 0.f, 0.f};
#pragma unroll
    for (int kh = 0; kh < 2; kh++)
#pragma unroll
        for (int et = 0; et < 4; et++) {
            bf16x8 bst = *(const bf16x8*)&Sw[0][et * 16 + fm][kh * 32 + quad * 8];
#pragma unroll
            for (int mt = 0; mt < 4; mt++)
                acc[mt][et] = MFMA16(aq[mt][kh], bst, acc[mt][et]);
        }
#pragma unroll
    for (int mt = 0; mt < 4; mt++)
#pragma unroll
        for (int r = 0; r < 4; r++) {
            float qd = dtab[wave * 64 + mt * 16 + quad * 4 + r + 1];
#pragma unroll
            for (int et = 0; et < 4; et++) acc[mt][et][r] *= qd;
        }

    // intra over k-tiles (uniform loop; wave computes only nt <= wave)
    const int sn = t & 63, sc0 = t >> 6;
    for (int nt = 0; nt < 4; nt++) {
        __syncthreads();   // prior reads of kS/vT/stT done before restage
        // stage kS via global_load_lds, chunk-swizzled (pos p holds p^(n&7))
#pragma unroll
        for (int i = 0; i < 2; i++) {
            int row = i * 32 + wave * 8 + (lane >> 3);
            const ushort_t* g = base + (long)(nt * 64 + row) * QKVW + HDIM +
                                (((lane & 7) ^ (lane >> 3)) * 8);
            GLOAD_LDS16(g, &kS[(i * 32 + wave * 8) * 64]);
        }
        // stage vT tile [e][n]
#pragma unroll
        for (int cc = 0; cc < 2; cc++) {
            int c = sc0 + cc * 4;
            bf16x8 v8 = *(const bf16x8*)(base + (long)(nt * 64 + sn) * QKVW +
                                         2 * HDIM + c * 8);
#pragma unroll
            for (int j = 0; j < 8; j++) vT[c * 8 + j][sn] = (ushort_t)v8[j];
        }
        __syncthreads();

        if (nt <= wave) {
            // S^T = k @ q^T : C row = n, col = m
            floatx4 sacc[4][4];
#pragma unroll
            for (int i = 0; i < 4; i++)
#pragma unroll
                for (int j = 0; j < 4; j++) sacc[i][j] = (floatx4){0.f, 0.f, 0.f, 0.f};
#pragma unroll
            for (int kh = 0; kh < 2; kh++) {
                bf16x8 ak[4];
#pragma unroll
                for (int snt = 0; snt < 4; snt++) {
                    int n = snt * 16 + fm;
                    int pos = (kh * 4 + quad) ^ (n & 7);
                    ak[snt] = *(const bf16x8*)&kS[n * 64 + pos * 8];
                }
#pragma unroll
                for (int snt = 0; snt < 4; snt++)
#pragma unroll
                    for (int smt = 0; smt < 4; smt++)
                        sacc[snt][smt] = MFMA16(ak[snt], aq[smt][kh], sacc[snt][smt]);
            }
            // decay + mask + bf16, store Sw[wave][m][n] (ushort4 rows)
#pragma unroll
            for (int snt = 0; snt < 4; snt++)
#pragma unroll
                for (int smt = 0; smt < 4; smt++) {
                    int mloc = smt * 16 + fm;              // 0..63 in wave rows
                    float rf = dtab[wave * 64 + mloc - nt * 64];
                    ushortx4 o;
#pragma unroll
                    for (int r = 0; r < 4; r++) {
                        int nloc = snt * 16 + quad * 4 + r;
                        float v = sacc[snt][smt][r] * rf * etab[nloc];
                        if (nt == wave && mloc < nloc) v = 0.f;
                        o[r] = f2bf(v);
                    }
                    *(ushortx4*)&Sw[wave][mloc][snt * 16 + quad * 4] = o;
                }
            // intra: acc += S @ v  (A = Sw rows m, B = vT rows e)
#pragma unroll
            for (int kh = 0; kh < 2; kh++) {
                bf16x8 as[4];
#pragma unroll
                for (int mt = 0; mt < 4; mt++)
                    as[mt] = *(const bf16x8*)&Sw[wave][mt * 16 + fm][kh * 32 + quad * 8];
#pragma unroll
                for (int et = 0; et < 4; et++) {
                    bf16x8 bv = *(const bf16x8*)&vT[et * 16 + fm][kh * 32 + quad * 8];
#pragma unroll
                    for (int mt = 0; mt < 4; mt++)
                        acc[mt][et] = MFMA16(as[mt], bv, acc[mt][et]);
                }
            }
        }
    }

    // write hidden[token][h*64+e] (coalesced 64B per quad)
#pragma unroll
    for (int mt = 0; mt < 4; mt++)
#pragma unroll
        for (int r = 0; r < 4; r++) {
            long tok = (long)b * BLK + wave * 64 + mt * 16 + quad * 4 + r;
            float* hp = hidden + tok * HIDDEN + h * HDIM;
#pragma unroll
            for (int et = 0; et < 4; et++)
                hp[et * 16 + fm] = acc[mt][et][r];
        }
}

// ---------------------------------------------------------------------------
// RMSNorm over rows (in place). grid NTOK, 256 threads.
// ---------------------------------------------------------------------------
__global__ __launch_bounds__(256) void rmsnorm_rows(
    float* __restrict__ hidden, const float* __restrict__ w) {
    const int row = blockIdx.x, t = threadIdx.x;
    float* hp = hidden + (long)row * HIDDEN;
    float4 a = *(const float4*)(hp + (t << 2));
    float4 b = *(const float4*)(hp + 1024 + (t << 2));
    float ss = a.x * a.x + a.y * a.y + a.z * a.z + a.w * a.w +
               b.x * b.x + b.y * b.y + b.z * b.z + b.w * b.w;
#pragma unroll
    for (int off = 32; off > 0; off >>= 1) ss += __shfl_down(ss, off);
    __shared__ float red[4];
    if ((t & 63) == 0) red[t >> 6] = ss;
    __syncthreads();
    float tot = red[0] + red[1] + red[2] + red[3];
    float scale = rsqrtf(tot * (1.f / HIDDEN) + 1e-5f);
    float4 wa = *(const float4*)(w + (t << 2));
    float4 wb = *(const float4*)(w + 1024 + (t << 2));
    a.x *= scale * wa.x; a.y *= scale * wa.y; a.z *= scale * wa.z; a.w *= scale * wa.w;
    b.x *= scale * wb.x; b.y *= scale * wb.y; b.z *= scale * wb.z; b.w *= scale * wb.w;
    *(float4*)(hp + (t << 2)) = a;
    *(float4*)(hp + 1024 + (t << 2)) = b;
}

// ---------------------------------------------------------------------------
extern "C" void kernel_launch(void* const* d_in, const int* in_sizes, int n_in,
                              void* d_out, int out_size, void* d_ws, size_t ws_size,
                              hipStream_t stream) {
    (void)in_sizes; (void)n_in; (void)out_size; (void)ws_size;
    const float* hs   = (const float*)d_in[0];
    const float* kv0  = (const float*)d_in[1];
    const float* Wqkv = (const float*)d_in[2];
    const float* Wg   = (const float*)d_in[3];
    const float* Wo   = (const float*)d_in[4];
    const float* nw   = (const float*)d_in[5];
    float* out = (float*)d_out;

    ushort_t* hs_h   = (ushort_t*)d_ws;
    ushort_t* wqkv_h = hs_h + (size_t)NTOK * HIDDEN;
    ushort_t* wg_h   = wqkv_h + (size_t)QKVW * HIDDEN;
    ushort_t* wo_h   = wg_h + (size_t)HIDDEN * HIDDEN;
    ushort_t* qkv_h  = wo_h + (size_t)HIDDEN * HIDDEN;
    float*    cs     = (float*)(qkv_h + (size_t)NTOK * QKVW);
    ushort_t* gated  = qkv_h;                    // reuse after attention

    cvt_bf16<<<(NTOK * HIDDEN / 8 + 255) / 256, 256, 0, stream>>>(
        hs, hs_h, NTOK * HIDDEN / 8);
    cvt_bf16<<<(QKVW * HIDDEN / 8 + 255) / 256, 256, 0, stream>>>(
        Wqkv, wqkv_h, QKVW * HIDDEN / 8);
    cvt_bf16<<<(HIDDEN * HIDDEN / 8 + 255) / 256, 256, 0, stream>>>(
        Wg, wg_h, HIDDEN * HIDDEN / 8);
    cvt_bf16<<<(HIDDEN * HIDDEN / 8 + 255) / 256, 256, 0, stream>>>(
        Wo, wo_h, HIDDEN * HIDDEN / 8);

    gemm256_bt<0, ushort_t><<<dim3(QKVW / 256, NTOK / 256), 512, 0, stream>>>(
        hs_h, wqkv_h, qkv_h, nullptr, NTOK, QKVW, HIDDEN);
    attn_contrib_mfma<<<dim3(NBLK, NHEAD), 256, 0, stream>>>(qkv_h, cs);
    attn_scan<<<dim3(NHEAD, 4), 256, 0, stream>>>(kv0, cs, cs);
    attn_core_mfma<<<dim3(NBLK, NHEAD), 256, 0, stream>>>(qkv_h, cs, out);
    rmsnorm_rows<<<NTOK, 256, 0, stream>>>(out, nw);
    gemm256_bt<2, ushort_t><<<dim3(HIDDEN / 256, NTOK / 256), 512, 0, stream>>>(
        hs_h, wg_h, gated, out, NTOK, HIDDEN, HIDDEN);
    gemm256_bt<1, float><<<dim3(HIDDEN / 256, NTOK / 256), 512, 0, stream>>>(
        gated, wo_h, out, nullptr, NTOK, HIDDEN, HIDDEN);
}

// Round 6
// 625.497 us; speedup vs baseline: 1.1419x; 1.0443x over previous
//
#include <hip/hip_runtime.h>

// Problem constants (fixed by reference)
#define NTOK   8192
#define HIDDEN 2048
#define NHEAD  32
#define HDIM   64
#define BLK    256
#define NBLK   32          // NTOK / BLK
#define QKVW   6144        // 3 * HIDDEN

typedef unsigned short ushort_t;
typedef __attribute__((ext_vector_type(8))) short bf16x8;   // 8 bf16 = 4 VGPRs
typedef __attribute__((ext_vector_type(4))) float floatx4;  // MFMA C/D
typedef __attribute__((ext_vector_type(4))) unsigned short ushortx4;

#define MFMA16(a, b, c) __builtin_amdgcn_mfma_f32_16x16x32_bf16(a, b, c, 0, 0, 0)

// slope[h] = 2^(-0.25*(h+1)) * (1 - 0/79 + 1e-5)
__device__ __forceinline__ float head_slope(int h) {
    return exp2f(-0.25f * (float)(h + 1)) * 1.00001f;
}

__device__ __forceinline__ ushort_t f2bf(float x) {
    unsigned int u = __float_as_uint(x);
    unsigned int r = (u + 0x7FFFu + ((u >> 16) & 1u)) >> 16;   // RNE
    return (ushort_t)r;
}
__device__ __forceinline__ float bf2f(ushort_t x) {
    return __uint_as_float(((unsigned int)x) << 16);
}
__device__ __forceinline__ void store1(float* p, float v) { *p = v; }
__device__ __forceinline__ void store1(ushort_t* p, float v) { *p = f2bf(v); }

// async global->LDS, 16B per lane (lds dest = wave-uniform base + lane*16;
// global source is per-lane)
#define GLOAD_LDS16(g, l)                                              \
    __builtin_amdgcn_global_load_lds(                                  \
        (const __attribute__((address_space(1))) void*)(g),            \
        (__attribute__((address_space(3))) void*)(l), 16, 0, 0)

// ---------------------------------------------------------------------------
// fp32 -> bf16 convert for all four staged tensors in ONE launch.
// Destinations are contiguous in the workspace (hs_h|wqkv_h|wg_h|wo_h),
// so dst offset is the global index; source picked by region.
// Region sizes in 8-elem units (compile-time):
//   n0 = NTOK*HIDDEN/8, n1 = QKVW*HIDDEN/8, n2 = n3 = HIDDEN*HIDDEN/8
// ---------------------------------------------------------------------------
#define CVT_N0 (NTOK * HIDDEN / 8)
#define CVT_N1 (QKVW * HIDDEN / 8)
#define CVT_N2 (HIDDEN * HIDDEN / 8)
#define CVT_NTOT (CVT_N0 + CVT_N1 + 2 * CVT_N2)

__global__ __launch_bounds__(256) void cvt_bf16_all(
    const float* __restrict__ s0, const float* __restrict__ s1,
    const float* __restrict__ s2, const float* __restrict__ s3,
    ushort_t* __restrict__ dst) {
    int i = blockIdx.x * 256 + threadIdx.x;
    if (i >= CVT_NTOT) return;
    const float* src;
    long si;
    if (i < CVT_N0)                    { src = s0; si = i; }
    else if (i < CVT_N0 + CVT_N1)      { src = s1; si = i - CVT_N0; }
    else if (i < CVT_N0 + CVT_N1 + CVT_N2) { src = s2; si = i - CVT_N0 - CVT_N1; }
    else                               { src = s3; si = i - CVT_N0 - CVT_N1 - CVT_N2; }
    float4 a = *(const float4*)(src + si * 8);
    float4 b = *(const float4*)(src + si * 8 + 4);
    ushort4 u0 = {f2bf(a.x), f2bf(a.y), f2bf(a.z), f2bf(a.w)};
    ushort4 u1 = {f2bf(b.x), f2bf(b.y), f2bf(b.z), f2bf(b.w)};
    long base = (long)i * 8;
    *(ushort4*)(dst + base) = u0;
    *(ushort4*)(dst + base + 4) = u1;
}

// ---------------------------------------------------------------------------
// 256x256-tile bf16 MFMA GEMM, 8-phase (m201) schedule — round-3 structure
// (empirical best: 244.8 us QKV, MfmaUtil 36%). DO NOT touch the barrier
// placement: removing the leading barrier was measured WORSE (round 4).
//
// NEW this round: grouped 2D XCD-local block mapping. Old mapping gave each
// XCD full bm-rows -> streamed the whole B panel (25 MB) per bm-row through
// a 4 MB L2 => FETCH_SIZE 5.5x over ideal. Now XCD x owns an 8bm x (chunk/8)bn
// rectangle, walked bn-major in 8-bm columns: ~32 concurrent blocks span
// 8 A-panels x 4 B-panels, both with dense L2 reuse. Bijective because
// nwg % 8 == 0 and nbm % 8 == 0 for all three GEMMs.
//
// BK=64, double-buffered: As/Bs[2][256*64] = 128 KB. One K-tile = 4 phases;
// each phase: {ds_reads} {stage quarter gloads} [lgkm predrain] s_barrier;
// lgkmcnt(0); sched_barrier; setprio(1); 16 MFMA; setprio(0); s_barrier.
// Staging recycles the CURRENT buffer quarter-by-quarter after its last
// read phase (A q0,q2: ph0->ph1; B all: ph1->ph2; A q1,q3: ph2->ph3).
// vmcnt(8) once per K-tile; drains to 0 only at the tail.
// LDS swizzle: chunk p of row r at position p^(r&7); linear LDS dest,
// inverse-permuted global source; fragment chunk (ks*4+quad)^(fm&7).
// 0 bank conflicts (verified by counter).
// ---------------------------------------------------------------------------
template <int EPI, typename OutT>
__global__ __launch_bounds__(512, 2) void gemm256_bt(
    const ushort_t* __restrict__ A, const ushort_t* __restrict__ B,
    OutT* __restrict__ C, const float* __restrict__ Mul,
    int M, int Ncol, int K) {
    __shared__ __align__(128) ushort_t As[2][256 * 64];   // 2 x 32 KB
    __shared__ __align__(128) ushort_t Bs[2][256 * 64];   // 2 x 32 KB

    const int t = threadIdx.x;
    const int wave = t >> 6, lane = t & 63;
    const int wm = wave >> 2, wn = wave & 3;            // 2 x 4 wave grid
    const int fm = lane & 15, quad = lane >> 4;

    // grouped 2D XCD-local mapping (bijective: nwg%8==0, nbm%8==0)
    const int nbn = Ncol >> 8;
    const int nbm = M >> 8;
    const int flat = blockIdx.y * gridDim.x + blockIdx.x;
    const int nwg = nbn * nbm;
    const int r = (flat & 7) * (nwg >> 3) + (flat >> 3);   // XCD-contig rank
    const int g = r / (8 * nbn);                           // bm-group of 8
    const int rg = r - g * 8 * nbn;
    const int bn = rg >> 3;
    const int bm = g * 8 + (rg & 7);

    // staging: thread t -> row t>>3 (0..63 within a 64-row quarter),
    // phys chunk t&7; fetches global chunk (t&7)^(row&7).
    const int srow = t >> 3;
    const int schunk = ((t & 7) ^ (srow & 7)) << 3;     // elems
    const ushort_t* Ags = A + ((long)bm * 256 + srow) * K + schunk;
    const ushort_t* Bgs = B + ((long)bn * 256 + srow) * K + schunk;
    const int sdst = wave * 512;                        // ushorts (1KB/wave)

    // stage quarter q (rows q*64..q*64+63) of K-tile kt into buffer buf
#define STAGE_AQ(kt_, buf_, q_)                                          \
    GLOAD_LDS16(Ags + (long)(q_) * 64 * K + (long)(kt_) * 64,            \
                &As[buf_][(q_) * 4096 + sdst])
#define STAGE_BQ(kt_, buf_, q_)                                          \
    GLOAD_LDS16(Bgs + (long)(q_) * 64 * K + (long)(kt_) * 64,            \
                &Bs[buf_][(q_) * 4096 + sdst])

    // fragment addressing (ushort offsets; row stride 64 = 128 B)
    const int aoff = (wm * 128 + fm) * 64;
    const int boff = (wn * 64 + fm) * 64;
    const int cx0 = ((quad ^ (fm & 7)) << 3);           // ks=0 chunk
    const int cx1 = (((4 + quad) ^ (fm & 7)) << 3);     // ks=1 chunk

    floatx4 acc[8][4];
#pragma unroll
    for (int i = 0; i < 8; i++)
#pragma unroll
        for (int j = 0; j < 4; j++) acc[i][j] = (floatx4){0.f, 0.f, 0.f, 0.f};

    const int NKT = K >> 6;                              // 32
    // prologue: tiles 0 (buf0) and 1 (buf1), 16 loads/thread
#pragma unroll
    for (int q = 0; q < 4; q++) STAGE_AQ(0, 0, q);
#pragma unroll
    for (int q = 0; q < 4; q++) STAGE_BQ(0, 0, q);
#pragma unroll
    for (int q = 0; q < 4; q++) STAGE_AQ(1, 1, q);
#pragma unroll
    for (int q = 0; q < 4; q++) STAGE_BQ(1, 1, q);
    asm volatile("s_waitcnt vmcnt(8)" ::: "memory");     // tile 0 landed
    __builtin_amdgcn_s_barrier();

    for (int kt = 0; kt < NKT; ++kt) {
        const int cur = kt & 1;
        const ushort_t* Ab = &As[cur][0];
        const ushort_t* Bb = &Bs[cur][0];
        const bool st = (kt + 2 < NKT);                  // stage into cur

        bf16x8 a0[4][2], a1[4][2], bl[2][2], bh[2][2];

        // ---------------- phase 0: quadrant (mh0, nh0) ----------------
#pragma unroll
        for (int mt = 0; mt < 4; ++mt) {
            a0[mt][0] = *(const bf16x8*)&Ab[aoff + mt * 1024 + cx0];
            a0[mt][1] = *(const bf16x8*)&Ab[aoff + mt * 1024 + cx1];
        }
#pragma unroll
        for (int nt = 0; nt < 2; ++nt) {
            bl[nt][0] = *(const bf16x8*)&Bb[boff + nt * 1024 + cx0];
            bl[nt][1] = *(const bf16x8*)&Bb[boff + nt * 1024 + cx1];
        }
        asm volatile("s_waitcnt lgkmcnt(8)" ::: "memory");   // m201 pre-drain
        __builtin_amdgcn_s_barrier();
        asm volatile("s_waitcnt lgkmcnt(0)" ::: "memory");
        __builtin_amdgcn_sched_barrier(0);
        __builtin_amdgcn_s_setprio(1);
#pragma unroll
        for (int mt = 0; mt < 4; ++mt)
#pragma unroll
            for (int nt = 0; nt < 2; ++nt) {
                acc[mt][nt] = MFMA16(a0[mt][0], bl[nt][0], acc[mt][nt]);
                acc[mt][nt] = MFMA16(a0[mt][1], bl[nt][1], acc[mt][nt]);
            }
        __builtin_amdgcn_s_setprio(0);
        __builtin_amdgcn_s_barrier();

        // ---------------- phase 1: quadrant (mh0, nh1) ----------------
#pragma unroll
        for (int nt = 0; nt < 2; ++nt) {
            bh[nt][0] = *(const bf16x8*)&Bb[boff + 2048 + nt * 1024 + cx0];
            bh[nt][1] = *(const bf16x8*)&Bb[boff + 2048 + nt * 1024 + cx1];
        }
        if (st) { STAGE_AQ(kt + 2, cur, 0); STAGE_AQ(kt + 2, cur, 2); }
        __builtin_amdgcn_s_barrier();
        asm volatile("s_waitcnt lgkmcnt(0)" ::: "memory");
        __builtin_amdgcn_sched_barrier(0);
        __builtin_amdgcn_s_setprio(1);
#pragma unroll
        for (int mt = 0; mt < 4; ++mt)
#pragma unroll
            for (int nt = 0; nt < 2; ++nt) {
                acc[mt][2 + nt] = MFMA16(a0[mt][0], bh[nt][0], acc[mt][2 + nt]);
                acc[mt][2 + nt] = MFMA16(a0[mt][1], bh[nt][1], acc[mt][2 + nt]);
            }
        __builtin_amdgcn_s_setprio(0);
        __builtin_amdgcn_s_barrier();

        // ---------------- phase 2: quadrant (mh1, nh1) ----------------
#pragma unroll
        for (int mt = 0; mt < 4; ++mt) {
            a1[mt][0] = *(const bf16x8*)&Ab[aoff + 4096 + mt * 1024 + cx0];
            a1[mt][1] = *(const bf16x8*)&Ab[aoff + 4096 + mt * 1024 + cx1];
        }
        if (st) {
            STAGE_BQ(kt + 2, cur, 0); STAGE_BQ(kt + 2, cur, 1);
            STAGE_BQ(kt + 2, cur, 2); STAGE_BQ(kt + 2, cur, 3);
        }
        __builtin_amdgcn_s_barrier();
        asm volatile("s_waitcnt lgkmcnt(0)" ::: "memory");
        __builtin_amdgcn_sched_barrier(0);
        __builtin_amdgcn_s_setprio(1);
#pragma unroll
        for (int mt = 0; mt < 4; ++mt)
#pragma unroll
            for (int nt = 0; nt < 2; ++nt) {
                acc[4 + mt][2 + nt] = MFMA16(a1[mt][0], bh[nt][0], acc[4 + mt][2 + nt]);
                acc[4 + mt][2 + nt] = MFMA16(a1[mt][1], bh[nt][1], acc[4 + mt][2 + nt]);
            }
        __builtin_amdgcn_s_setprio(0);
        __builtin_amdgcn_s_barrier();

        // ---------------- phase 3: quadrant (mh1, nh0) ----------------
        if (st) { STAGE_AQ(kt + 2, cur, 1); STAGE_AQ(kt + 2, cur, 3); }
        __builtin_amdgcn_s_barrier();
        __builtin_amdgcn_sched_barrier(0);
        __builtin_amdgcn_s_setprio(1);
#pragma unroll
        for (int mt = 0; mt < 4; ++mt)
#pragma unroll
            for (int nt = 0; nt < 2; ++nt) {
                acc[4 + mt][nt] = MFMA16(a1[mt][0], bl[nt][0], acc[4 + mt][nt]);
                acc[4 + mt][nt] = MFMA16(a1[mt][1], bl[nt][1], acc[4 + mt][nt]);
            }
        __builtin_amdgcn_s_setprio(0);

        // ---- end of tile: counted wait (tile kt+1 landed; kt+2 in flight)
        if (kt + 2 < NKT) {
            asm volatile("s_waitcnt vmcnt(8)" ::: "memory");
        } else if (kt + 1 < NKT) {
            asm volatile("s_waitcnt vmcnt(0)" ::: "memory");
        }
        __builtin_amdgcn_s_barrier();
    }
#undef STAGE_AQ
#undef STAGE_BQ

    // epilogue
#pragma unroll
    for (int mt = 0; mt < 8; ++mt)
#pragma unroll
        for (int nt = 0; nt < 4; ++nt) {
            long col = (long)bn * 256 + wn * 64 + nt * 16 + fm;
#pragma unroll
            for (int r2 = 0; r2 < 4; ++r2) {
                long row = (long)bm * 256 + wm * 128 + mt * 16 + quad * 4 + r2;
                long idx = row * Ncol + col;
                float x = acc[mt][nt][r2];
                float o;
                if (EPI == 0)      o = x / (1.f + expf(-x));          // silu
                else if (EPI == 1) o = x;                             // plain
                else               o = Mul[idx] / (1.f + expf(-x));   // gate
                store1(C + idx, o);
            }
        }
}

// ---------------------------------------------------------------------------
// MFMA contrib: contrib[h][b][d][e] = sum_n kd[n]*k[n][d]*v[n][e].
// Wave w owns d rows w*16..+16, loops 4 token-tiles of 64 (K accumulate).
// ---------------------------------------------------------------------------
__global__ __launch_bounds__(256) void attn_contrib_mfma(
    const ushort_t* __restrict__ qkv, float* __restrict__ contrib) {
    const int b = blockIdx.x, h = blockIdx.y;
    const float s = head_slope(h);
    __shared__ ushort_t kdT[64][72];   // [d][n]  k*kdecay, rows 144B
    __shared__ ushort_t vT[64][72];    // [e][n]
    const int t = threadIdx.x, wave = t >> 6, lane = t & 63;
    const int fm = lane & 15, quad = lane >> 4;
    const ushort_t* base = qkv + (long)(b * BLK) * QKVW + h * (3 * HDIM);

    floatx4 acc[4];
#pragma unroll
    for (int e = 0; e < 4; e++) acc[e] = (floatx4){0.f, 0.f, 0.f, 0.f};

    const int sn = t & 63;             // token within tile
    const int sc0 = t >> 6;            // chunk 0..3 (+4)

    for (int tt = 0; tt < 4; tt++) {
        __syncthreads();
        int tok = tt * 64 + sn;
        float kd = expf(-s * (float)(BLK - 1 - tok));
#pragma unroll
        for (int cc = 0; cc < 2; cc++) {
            int c = sc0 + cc * 4;
            bf16x8 k8 = *(const bf16x8*)(base + (long)tok * QKVW + HDIM + c * 8);
            bf16x8 v8 = *(const bf16x8*)(base + (long)tok * QKVW + 2 * HDIM + c * 8);
#pragma unroll
            for (int j = 0; j < 8; j++) {
                kdT[c * 8 + j][sn] = f2bf(bf2f((ushort_t)k8[j]) * kd);
                vT[c * 8 + j][sn]  = (ushort_t)v8[j];
            }
        }
        __syncthreads();
#pragma unroll
        for (int kh = 0; kh < 2; kh++) {
            bf16x8 a = *(const bf16x8*)&kdT[wave * 16 + fm][kh * 32 + quad * 8];
#pragma unroll
            for (int e = 0; e < 4; e++) {
                bf16x8 bb = *(const bf16x8*)&vT[e * 16 + fm][kh * 32 + quad * 8];
                acc[e] = MFMA16(a, bb, acc[e]);
            }
        }
    }
    float* outp = contrib + ((long)(h * NBLK + b)) * 4096;
#pragma unroll
    for (int e = 0; e < 4; e++)
#pragma unroll
        for (int r = 0; r < 4; r++) {
            int d = wave * 16 + quad * 4 + r;
            outp[d * 64 + e * 16 + fm] = acc[e][r];
        }
}

// ---------------------------------------------------------------------------
// Sequential decay scan over blocks (in-place safe).
// grid (NHEAD, 4); each block owns a 1024-float segment; float4/thread.
// ---------------------------------------------------------------------------
__global__ __launch_bounds__(256) void attn_scan(
    const float* __restrict__ kv0, const float* __restrict__ contrib,
    float* __restrict__ states) {
    const int h = blockIdx.x, seg = blockIdx.y, t = threadIdx.x;
    const float s  = head_slope(h);
    const float bd = expf(-s * (float)BLK);
    const int off = seg * 1024 + t * 4;
    float4 st = *(const float4*)(kv0 + (long)h * 4096 + off);
    for (int b = 0; b < NBLK; b++) {
        const long base = ((long)(h * NBLK + b)) * 4096 + off;
        float4 c = *(const float4*)(contrib + base);
        *(float4*)(states + base) = st;
        st.x = bd * st.x + c.x;
        st.y = bd * st.y + c.y;
        st.z = bd * st.z + c.z;
        st.w = bd * st.w + c.w;
    }
}

// ---------------------------------------------------------------------------
// MFMA attention core per (h,b):
//   out = diag(qdec)*(q @ state) + ((q@k^T) .* decay) @ v
// Wave w owns q rows w*64..+64. S computed transposed (A=k, B=q) so the
// decayed tile stores to Sw[m][n] as ushort4 rows; then intra A=Sw, B=vT.
// ---------------------------------------------------------------------------
__global__ __launch_bounds__(256) void attn_core_mfma(
    const ushort_t* __restrict__ qkv, const float* __restrict__ states,
    float* __restrict__ hidden) {
    const int b = blockIdx.x, h = blockIdx.y;
    const float s = head_slope(h);
    __shared__ ushort_t Sw[4][64][72];   // per-wave S tile; Sw[0] = stT first
    __shared__ ushort_t kS[64 * 64];     // k tile [n][d], 128B rows, swizzled
    __shared__ ushort_t vT[64][72];      // v tile [e][n]
    __shared__ float dtab[257];          // exp(-s*delta)
    __shared__ float etab[64];           // exp(+s*j)
    const int t = threadIdx.x, wave = t >> 6, lane = t & 63;
    const int fm = lane & 15, quad = lane >> 4;
    const ushort_t* base = qkv + (long)(b * BLK) * QKVW + h * (3 * HDIM);

    dtab[t] = expf(-s * (float)t);
    if (t == 0) dtab[256] = expf(-s * 256.f);
    if (t < 64) etab[t] = expf(s * (float)t);

    {   // stT = Sw[0]: [e][d] <- states (bf16)
        const float* sp = states + ((long)(h * NBLK + b)) * 4096;
#pragma unroll
        for (int i = 0; i < 4; i++) {
            int idx = t + 256 * i;
            int d = idx >> 4, e4 = (idx & 15) * 4;
            float4 st4 = *(const float4*)(sp + d * 64 + e4);
            Sw[0][e4 + 0][d] = f2bf(st4.x);
            Sw[0][e4 + 1][d] = f2bf(st4.y);
            Sw[0][e4 + 2][d] = f2bf(st4.z);
            Sw[0][e4 + 3][d] = f2bf(st4.w);
        }
    }

    // q fragments from global (read once)
    bf16x8 aq[4][2];
#pragma unroll
    for (int mt = 0; mt < 4; mt++)
#pragma unroll
        for (int kh = 0; kh < 2; kh++)
            aq[mt][kh] = *(const bf16x8*)(base +
                (long)(wave * 64 + mt * 16 + fm) * QKVW + kh * 32 + quad * 8);

    __syncthreads();

    // inter = q @ state, then row-scale by qdecay
    floatx4 acc[4][4];
#pragma unroll
    for (int i = 0; i < 4; i++)
#pragma unroll
        for (int j = 0; j < 4; j++) acc[i][j] = (floatx4){0.f, 0.f, 0.f, 0.f};
#pragma unroll
    for (int kh = 0; kh < 2; kh++)
#pragma unroll
        for (int et = 0; et < 4; et++) {
            bf16x8 bst = *(const bf16x8*)&Sw[0][et * 16 + fm][kh * 32 + quad * 8];
#pragma unroll
            for (int mt = 0; mt < 4; mt++)
                acc[mt][et] = MFMA16(aq[mt][kh], bst, acc[mt][et]);
        }
#pragma unroll
    for (int mt = 0; mt < 4; mt++)
#pragma unroll
        for (int r = 0; r < 4; r++) {
            float qd = dtab[wave * 64 + mt * 16 + quad * 4 + r + 1];
#pragma unroll
            for (int et = 0; et < 4; et++) acc[mt][et][r] *= qd;
        }

    // intra over k-tiles (uniform loop; wave computes only nt <= wave)
    const int sn = t & 63, sc0 = t >> 6;
    for (int nt = 0; nt < 4; nt++) {
        __syncthreads();   // prior reads of kS/vT/stT done before restage
        // stage kS via global_load_lds, chunk-swizzled (pos p holds p^(n&7))
#pragma unroll
        for (int i = 0; i < 2; i++) {
            int row = i * 32 + wave * 8 + (lane >> 3);
            const ushort_t* g = base + (long)(nt * 64 + row) * QKVW + HDIM +
                                (((lane & 7) ^ (lane >> 3)) * 8);
            GLOAD_LDS16(g, &kS[(i * 32 + wave * 8) * 64]);
        }
        // stage vT tile [e][n]
#pragma unroll
        for (int cc = 0; cc < 2; cc++) {
            int c = sc0 + cc * 4;
            bf16x8 v8 = *(const bf16x8*)(base + (long)(nt * 64 + sn) * QKVW +
                                         2 * HDIM + c * 8);
#pragma unroll
            for (int j = 0; j < 8; j++) vT[c * 8 + j][sn] = (ushort_t)v8[j];
        }
        __syncthreads();

        if (nt <= wave) {
            // S^T = k @ q^T : C row = n, col = m
            floatx4 sacc[4][4];
#pragma unroll
            for (int i = 0; i < 4; i++)
#pragma unroll
                for (int j = 0; j < 4; j++) sacc[i][j] = (floatx4){0.f, 0.f, 0.f, 0.f};
#pragma unroll
            for (int kh = 0; kh < 2; kh++) {
                bf16x8 ak[4];
#pragma unroll
                for (int snt = 0; snt < 4; snt++) {
                    int n = snt * 16 + fm;
                    int pos = (kh * 4 + quad) ^ (n & 7);
                    ak[snt] = *(const bf16x8*)&kS[n * 64 + pos * 8];
                }
#pragma unroll
                for (int snt = 0; snt < 4; snt++)
#pragma unroll
                    for (int smt = 0; smt < 4; smt++)
                        sacc[snt][smt] = MFMA16(ak[snt], aq[smt][kh], sacc[snt][smt]);
            }
            // decay + mask + bf16, store Sw[wave][m][n] (ushort4 rows)
#pragma unroll
            for (int snt = 0; snt < 4; snt++)
#pragma unroll
                for (int smt = 0; smt < 4; smt++) {
                    int mloc = smt * 16 + fm;              // 0..63 in wave rows
                    float rf = dtab[wave * 64 + mloc - nt * 64];
                    ushortx4 o;
#pragma unroll
                    for (int r = 0; r < 4; r++) {
                        int nloc = snt * 16 + quad * 4 + r;
                        float v = sacc[snt][smt][r] * rf * etab[nloc];
                        if (nt == wave && mloc < nloc) v = 0.f;
                        o[r] = f2bf(v);
                    }
                    *(ushortx4*)&Sw[wave][mloc][snt * 16 + quad * 4] = o;
                }
            // intra: acc += S @ v  (A = Sw rows m, B = vT rows e)
#pragma unroll
            for (int kh = 0; kh < 2; kh++) {
                bf16x8 as[4];
#pragma unroll
                for (int mt = 0; mt < 4; mt++)
                    as[mt] = *(const bf16x8*)&Sw[wave][mt * 16 + fm][kh * 32 + quad * 8];
#pragma unroll
                for (int et = 0; et < 4; et++) {
                    bf16x8 bv = *(const bf16x8*)&vT[et * 16 + fm][kh * 32 + quad * 8];
#pragma unroll
                    for (int mt = 0; mt < 4; mt++)
                        acc[mt][et] = MFMA16(as[mt], bv, acc[mt][et]);
                }
            }
        }
    }

    // write hidden[token][h*64+e] (coalesced 64B per quad)
#pragma unroll
    for (int mt = 0; mt < 4; mt++)
#pragma unroll
        for (int r = 0; r < 4; r++) {
            long tok = (long)b * BLK + wave * 64 + mt * 16 + quad * 4 + r;
            float* hp = hidden + tok * HIDDEN + h * HDIM;
#pragma unroll
            for (int et = 0; et < 4; et++)
                hp[et * 16 + fm] = acc[mt][et][r];
        }
}

// ---------------------------------------------------------------------------
// RMSNorm over rows (in place). grid NTOK, 256 threads.
// ---------------------------------------------------------------------------
__global__ __launch_bounds__(256) void rmsnorm_rows(
    float* __restrict__ hidden, const float* __restrict__ w) {
    const int row = blockIdx.x, t = threadIdx.x;
    float* hp = hidden + (long)row * HIDDEN;
    float4 a = *(const float4*)(hp + (t << 2));
    float4 b = *(const float4*)(hp + 1024 + (t << 2));
    float ss = a.x * a.x + a.y * a.y + a.z * a.z + a.w * a.w +
               b.x * b.x + b.y * b.y + b.z * b.z + b.w * b.w;
#pragma unroll
    for (int off = 32; off > 0; off >>= 1) ss += __shfl_down(ss, off);
    __shared__ float red[4];
    if ((t & 63) == 0) red[t >> 6] = ss;
    __syncthreads();
    float tot = red[0] + red[1] + red[2] + red[3];
    float scale = rsqrtf(tot * (1.f / HIDDEN) + 1e-5f);
    float4 wa = *(const float4*)(w + (t << 2));
    float4 wb = *(const float4*)(w + 1024 + (t << 2));
    a.x *= scale * wa.x; a.y *= scale * wa.y; a.z *= scale * wa.z; a.w *= scale * wa.w;
    b.x *= scale * wb.x; b.y *= scale * wb.y; b.z *= scale * wb.z; b.w *= scale * wb.w;
    *(float4*)(hp + (t << 2)) = a;
    *(float4*)(hp + 1024 + (t << 2)) = b;
}

// ---------------------------------------------------------------------------
extern "C" void kernel_launch(void* const* d_in, const int* in_sizes, int n_in,
                              void* d_out, int out_size, void* d_ws, size_t ws_size,
                              hipStream_t stream) {
    (void)in_sizes; (void)n_in; (void)out_size; (void)ws_size;
    const float* hs   = (const float*)d_in[0];
    const float* kv0  = (const float*)d_in[1];
    const float* Wqkv = (const float*)d_in[2];
    const float* Wg   = (const float*)d_in[3];
    const float* Wo   = (const float*)d_in[4];
    const float* nw   = (const float*)d_in[5];
    float* out = (float*)d_out;

    ushort_t* hs_h   = (ushort_t*)d_ws;
    ushort_t* wqkv_h = hs_h + (size_t)NTOK * HIDDEN;
    ushort_t* wg_h   = wqkv_h + (size_t)QKVW * HIDDEN;
    ushort_t* wo_h   = wg_h + (size_t)HIDDEN * HIDDEN;
    ushort_t* qkv_h  = wo_h + (size_t)HIDDEN * HIDDEN;
    float*    cs     = (float*)(qkv_h + (size_t)NTOK * QKVW);
    ushort_t* gated  = qkv_h;                    // reuse after attention

    cvt_bf16_all<<<(CVT_NTOT + 255) / 256, 256, 0, stream>>>(
        hs, Wqkv, Wg, Wo, hs_h);

    gemm256_bt<0, ushort_t><<<dim3(QKVW / 256, NTOK / 256), 512, 0, stream>>>(
        hs_h, wqkv_h, qkv_h, nullptr, NTOK, QKVW, HIDDEN);
    attn_contrib_mfma<<<dim3(NBLK, NHEAD), 256, 0, stream>>>(qkv_h, cs);
    attn_scan<<<dim3(NHEAD, 4), 256, 0, stream>>>(kv0, cs, cs);
    attn_core_mfma<<<dim3(NBLK, NHEAD), 256, 0, stream>>>(qkv_h, cs, out);
    rmsnorm_rows<<<NTOK, 256, 0, stream>>>(out, nw);
    gemm256_bt<2, ushort_t><<<dim3(HIDDEN / 256, NTOK / 256), 512, 0, stream>>>(
        hs_h, wg_h, gated, out, NTOK, HIDDEN, HIDDEN);
    gemm256_bt<1, float><<<dim3(HIDDEN / 256, NTOK / 256), 512, 0, stream>>>(
        gated, wo_h, out, nullptr, NTOK, HIDDEN, HIDDEN);
}